// Round 3
// baseline (586.443 us; speedup 1.0000x reference)
//
#include <hip/hip_runtime.h>
#include <hip/hip_bf16.h>
#include <math.h>

// Problem constants (from reference)
#define Bq   4
#define Tq   512
#define Hq   512
#define Vq   32000
#define Sq   512
#define SDVq 300
#define TDVq 512
#define ROWS (Bq * Tq)            // 2048
#define OUTW (Vq + SDVq + TDVq)   // 32812
#define NUNITS 4000               // (ROWS/128) * (Vq/128) = 16 * 250
#define GBLK 768                  // persistent blocks = 256 CU * 3
#define PCOLS 512                 // padded partial width (500 used)

typedef __bf16 bf16x8 __attribute__((ext_vector_type(8)));
typedef float  fx4    __attribute__((ext_vector_type(4)));
typedef unsigned short ushort8 __attribute__((ext_vector_type(8)));

__device__ __forceinline__ void async16(const void* g, void* l) {
    __builtin_amdgcn_global_load_lds(
        (const __attribute__((address_space(1))) void*)g,
        (__attribute__((address_space(3))) void*)l, 16, 0, 0);
}

__device__ __forceinline__ float bf2f(unsigned short u) {
    union { unsigned int i; float f; } c;
    c.i = ((unsigned int)u) << 16;
    return c.f;
}

__device__ __forceinline__ int m3(int a) { return a >= 3 ? a - 3 : a; }

// -------------------------------------------------------------------------
// K1: p = softmax(h @ Wp + bp) per row; one wave per row.
__global__ void compute_p(const float* __restrict__ hiddens,
                          const float* __restrict__ Wp,
                          const float* __restrict__ bp,
                          float* __restrict__ p) {
    int row  = blockIdx.x;
    int lane = threadIdx.x;   // 64 lanes
    const float* h = hiddens + (size_t)row * Hq;
    float a0 = 0.f, a1 = 0.f, a2 = 0.f;
    for (int i = lane; i < Hq; i += 64) {
        float hv = h[i];
        a0 += hv * Wp[i * 3 + 0];
        a1 += hv * Wp[i * 3 + 1];
        a2 += hv * Wp[i * 3 + 2];
    }
    for (int off = 32; off > 0; off >>= 1) {
        a0 += __shfl_down(a0, off);
        a1 += __shfl_down(a1, off);
        a2 += __shfl_down(a2, off);
    }
    if (lane == 0) {
        float l0 = a0 + bp[0], l1 = a1 + bp[1], l2 = a2 + bp[2];
        float M  = fmaxf(l0, fmaxf(l1, l2));
        float e0 = expf(l0 - M), e1 = expf(l1 - M), e2 = expf(l2 - M);
        float inv = 1.f / (e0 + e1 + e2);
        p[row * 3 + 0] = e0 * inv;
        p[row * 3 + 1] = e1 * inv;
        p[row * 3 + 2] = e2 * inv;
    }
}

// -------------------------------------------------------------------------
// K2: extract one-hot index per map row (argmax). One wave per row.
__global__ void extract_idx(const float* __restrict__ map, int ncols,
                            int* __restrict__ idx) {
    int row  = blockIdx.x;
    int lane = threadIdx.x;
    const float* r = map + (size_t)row * ncols;
    float best = -1.f; int bi = 0;
    for (int i = lane; i < ncols; i += 64) {
        float v = r[i];
        if (v > best) { best = v; bi = i; }
    }
    for (int off = 32; off > 0; off >>= 1) {
        float ob  = __shfl_down(best, off);
        int   obi = __shfl_down(bi, off);
        if (ob > best) { best = ob; bi = obi; }
    }
    if (lane == 0) idx[row] = bi;
}

// -------------------------------------------------------------------------
// Conversion: hiddens fp32 -> bf16 (same layout, k contiguous)
__global__ __launch_bounds__(256)
void convert_a(const float* __restrict__ in, __hip_bfloat16* __restrict__ o) {
    int i = blockIdx.x * 256 + threadIdx.x;
    float4 v = ((const float4*)in)[i];
    __hip_bfloat16* op = o + (size_t)i * 4;
    op[0] = __float2bfloat16(v.x);
    op[1] = __float2bfloat16(v.y);
    op[2] = __float2bfloat16(v.z);
    op[3] = __float2bfloat16(v.w);
}

// Transpose+convert: Wv (512 x 32000 fp32) -> Wt (32000 x 512 bf16)
__global__ __launch_bounds__(256)
void transpose_wv(const float* __restrict__ Wv, __hip_bfloat16* __restrict__ Wt) {
    __shared__ float t[32][33];
    int n0 = blockIdx.x * 32, k0 = blockIdx.y * 32;
    int tx = threadIdx.x, ty = threadIdx.y;   // 32 x 8
#pragma unroll
    for (int r = 0; r < 4; ++r)
        t[ty + r * 8][tx] = Wv[(size_t)(k0 + ty + r * 8) * Vq + n0 + tx];
    __syncthreads();
#pragma unroll
    for (int r = 0; r < 4; ++r)
        Wt[(size_t)(n0 + ty + r * 8) * Hq + k0 + tx] =
            __float2bfloat16(t[tx][ty + r * 8]);
}

// -------------------------------------------------------------------------
// K3: PERSISTENT bf16 MFMA GEMM. 768 blocks (3/CU), each owning a contiguous
// chunk of ~5.2 units (unit = one 128x128 output tile; nb=u>>4, mb=u&15).
// The 3-deep LDS ring + counted vmcnt(4) prefetch runs CONTINUOUSLY across
// unit boundaries: units u's last two K-steps stage unit u+1's first tiles.
// Epilogue per unit is barrier/LDS-free: e = exp(score+bv) -> bf16 (col 0 -> 0),
// row-sum partials via 16-lane shfl_xor + direct stores to partial[row][512]
// (column k = nb*2+wc; single writer per cell -> no atomics).
// vmcnt-safety at unit boundaries: vmcnt decrements IN ORDER, so vmcnt(4) at
// the first step of a unit drains the (older) prefetch loads plus epilogue
// stores, leaving only the 4 youngest ops. exp without max-subtract is safe:
// scores ~ N(0,1), softmax is shift-invariant.
__global__ __launch_bounds__(256, 3)
void gemm_persist(const __hip_bfloat16* __restrict__ A,
                  const __hip_bfloat16* __restrict__ Bt,
                  const float* __restrict__ bv,
                  __hip_bfloat16* __restrict__ eb,
                  float* __restrict__ partial) {
    __shared__ __align__(16) unsigned short As[3 * 4096];   // 24 KB
    __shared__ __align__(16) unsigned short Bs[3 * 4096];   // 24 KB
    int tid  = threadIdx.x;
    int wave = tid >> 6, lane = tid & 63;
    int wr = wave >> 1, wc = wave & 1;
    int lr = lane & 15;          // fragment row/col within 16
    int kq = lane >> 4;          // k-quad (0..3)

    // persistent work range: XCD x owns units [x*500, (x+1)*500)
    int x = blockIdx.x & 7, sl0 = blockIdx.x >> 3;
    int chunk = x * 96 + sl0;                    // 0..767
    int u0 = (chunk * 125) / 24;                 // == chunk*NUNITS/GBLK
    int u1 = ((chunk + 1) * 125) / 24;

    // staging: thread covers chunks {tid, tid+256} -> same row, kchunks +2
    int ar0 = tid & 127, ak0 = (tid >> 7) * 8;   // second chunk = +16 shorts
    const unsigned short* Ag = (const unsigned short*)A;
    const unsigned short* Bg = (const unsigned short*)Bt;
    unsigned short* Alds = &As[(wave << 6) * 8]; // wave-uniform LDS bases
    unsigned short* Blds = &Bs[(wave << 6) * 8];

#define SRC_A(u) (Ag + (size_t)(((u) & 15) * 128 + ar0) * Hq + ak0)
#define SRC_B(u) (Bg + (size_t)(((u) >> 4) * 128 + ar0) * Hq + ak0)
#define STAGE(pa, pb, k0s, slot) do {                                   \
        async16((pa) + (k0s),      Alds + (slot) * 4096);               \
        async16((pa) + (k0s) + 16, Alds + (slot) * 4096 + 2048);        \
        async16((pb) + (k0s),      Blds + (slot) * 4096);               \
        async16((pb) + (k0s) + 16, Blds + (slot) * 4096 + 2048);        \
    } while (0)

    const unsigned short* pA = SRC_A(u0);
    const unsigned short* pB = SRC_B(u0);
    STAGE(pA, pB, 0,  0);
    STAGE(pA, pB, 32, 1);

    int ph = 0;   // ring phase: slot of a unit's step tk is (ph + tk) % 3
    for (int u = u0; u < u1; ++u) {
        int nb = u >> 4;
        int bm = (u & 15) * 128, bn = nb * 128;
        bool hasN = (u + 1 < u1);
        int un = hasN ? u + 1 : u;
        const unsigned short* nA = SRC_A(un);
        const unsigned short* nB = SRC_B(un);

        float bvv[4];
#pragma unroll
        for (int j = 0; j < 4; ++j)
            bvv[j] = bv[bn + wc * 64 + j * 16 + lr];

        fx4 acc[4][4];
#pragma unroll
        for (int i = 0; i < 4; ++i)
#pragma unroll
            for (int j = 0; j < 4; ++j)
                acc[i][j] = (fx4){0.f, 0.f, 0.f, 0.f};

#pragma unroll
        for (int tk = 0; tk < 16; ++tk) {
            // drain my own stage for this step; keep the next in flight
            if (tk == 15 && !hasN)
                asm volatile("s_waitcnt vmcnt(0)" ::: "memory");
            else
                asm volatile("s_waitcnt vmcnt(4)" ::: "memory");
            __builtin_amdgcn_s_barrier();
            asm volatile("" ::: "memory");   // no LDS reads hoist above

            // prefetch step tk+2 (slot was fully read two steps ago)
            if (tk < 14)
                STAGE(pA, pB, (tk + 2) * 32, m3(ph + (tk + 2) % 3));
            else if (hasN)
                STAGE(nA, nB, (tk - 14) * 32, m3(ph + (tk + 2) % 3));

            int sl = m3(ph + tk % 3);
            const unsigned short* Asb = &As[sl * 4096];
            const unsigned short* Bsb = &Bs[sl * 4096];
            bf16x8 af[4], bfr[4];
#pragma unroll
            for (int i = 0; i < 4; ++i)
                af[i] = *(const bf16x8*)&Asb[(size_t)(kq * 128 + wr * 64 + i * 16 + lr) * 8];
#pragma unroll
            for (int j = 0; j < 4; ++j)
                bfr[j] = *(const bf16x8*)&Bsb[(size_t)(kq * 128 + wc * 64 + j * 16 + lr) * 8];

            __builtin_amdgcn_s_setprio(1);
#pragma unroll
            for (int i = 0; i < 4; ++i)
#pragma unroll
                for (int j = 0; j < 4; ++j)
                    acc[i][j] = __builtin_amdgcn_mfma_f32_16x16x32_bf16(
                        af[i], bfr[j], acc[i][j], 0, 0, 0);
            __builtin_amdgcn_s_setprio(0);

            // my ds_reads must finish before the next barrier releases the
            // DMA that overwrites this ring slot
            asm volatile("s_waitcnt lgkmcnt(0)" ::: "memory");
        }

        // ---- epilogue (no LDS, no barriers): e = exp(score+bias) -> bf16
        // C/D layout: col = lane&15, row = (lane>>4)*4 + reg
#pragma unroll
        for (int i = 0; i < 4; ++i) {
            int lrow = wr * 64 + i * 16 + kq * 4;
            float rsum[4] = {0.f, 0.f, 0.f, 0.f};
#pragma unroll
            for (int j = 0; j < 4; ++j) {
                int gc = bn + wc * 64 + j * 16 + lr;
#pragma unroll
                for (int r = 0; r < 4; ++r) {
                    float v = __expf(acc[i][j][r] + bvv[j]);
                    if (gc == 0) v = 0.f;   // scores[:,0] = -inf -> e = 0
                    eb[(size_t)(bm + lrow + r) * Vq + gc] = __float2bfloat16(v);
                    rsum[r] += v;
                }
            }
#pragma unroll
            for (int off = 1; off < 16; off <<= 1)
#pragma unroll
                for (int r = 0; r < 4; ++r)
                    rsum[r] += __shfl_xor(rsum[r], off);
            if (lr == 0) {
#pragma unroll
                for (int r = 0; r < 4; ++r)
                    partial[(size_t)(bm + lrow + r) * PCOLS + nb * 2 + wc] = rsum[r];
            }
        }

        pA = nA; pB = nB;
        ph = m3(ph + 1);   // 16 steps ≡ 1 (mod 3)
    }
#undef STAGE
#undef SRC_A
#undef SRC_B
}

// -------------------------------------------------------------------------
// K4: per-row finalize — one block per row:
//   0. S = sum over 500 partials (coalesced row read)
//   1. vocab probs = bf16(e) * pgen/S, fused vocab argmax
//   2. source scatter-add + write + argmax
//   3. target scatter-add + write + argmax
//   4. combine -> predictions
__global__ __launch_bounds__(256)
void finalize(const __hip_bfloat16* __restrict__ e_bf,
              const float* __restrict__ partial,
              const float* __restrict__ p,
              const float* __restrict__ src_att, const int* __restrict__ sidx,
              const float* __restrict__ tgt_att, const int* __restrict__ tidx,
              float* __restrict__ out, float* __restrict__ pred) {
    int row = blockIdx.x;
    int tid = threadIdx.x;
    int b   = row >> 9;   // /512
    __shared__ float accs[TDVq];
    __shared__ float bs[256];
    __shared__ int   is_[256];
    __shared__ float sred[4];

    // --- phase 0: S = sum_e -------------------------------------------------
    float s = 0.f;
    const float* prow = partial + (size_t)row * PCOLS;
    for (int k = tid; k < 500; k += 256) s += prow[k];
    for (int off = 32; off > 0; off >>= 1) s += __shfl_down(s, off);
    if ((tid & 63) == 0) sred[tid >> 6] = s;
    __syncthreads();
    float S     = sred[0] + sred[1] + sred[2] + sred[3];
    float scale = p[row * 3 + 2] / S;   // pgen / sum(e)

    // --- phase 1: vocab probs + argmax --------------------------------------
    const ushort8* er = (const ushort8*)(e_bf + (size_t)row * Vq);
    float* orow = out + (size_t)row * OUTW;
    float4* ov  = (float4*)orow;
    float bm_ = -1.f; int bi = 0;       // e >= 0; col 0 is exactly 0
    for (int i = tid; i < Vq / 8; i += 256) {
        ushort8 v = er[i];
        float f[8];
#pragma unroll
        for (int k = 0; k < 8; ++k) f[k] = bf2f(v[k]);
#pragma unroll
        for (int k = 0; k < 8; ++k)
            if (f[k] > bm_) { bm_ = f[k]; bi = i * 8 + k; }
        float4 lo = {f[0] * scale, f[1] * scale, f[2] * scale, f[3] * scale};
        float4 hi = {f[4] * scale, f[5] * scale, f[6] * scale, f[7] * scale};
        ov[2 * i]     = lo;
        ov[2 * i + 1] = hi;
    }
    bs[tid] = bm_; is_[tid] = bi;
    __syncthreads();
    for (int st = 128; st > 0; st >>= 1) {
        if (tid < st) {
            float v2 = bs[tid + st]; int i2 = is_[tid + st];
            if (v2 > bs[tid] || (v2 == bs[tid] && i2 < is_[tid])) {
                bs[tid] = v2; is_[tid] = i2;
            }
        }
        __syncthreads();
    }
    float cv0 = bs[0] * scale; int ci0 = is_[0];
    __syncthreads();

    // --- phase 2: source copy distribution ----------------------------------
    for (int i = tid; i < SDVq; i += 256) accs[i] = 0.f;
    __syncthreads();
    {
        const float* arow = src_att + (size_t)row * Sq;
        const int*   ib   = sidx + b * Sq;
        for (int s2 = tid; s2 < Sq; s2 += 256)
            atomicAdd(&accs[ib[s2]], arow[s2]);
    }
    __syncthreads();
    {
        float pc = p[row * 3 + 0];
        float bm2 = -INFINITY; int bi2 = 0;
        for (int v = tid; v < SDVq; v += 256) {
            float val = accs[v] * pc;
            orow[Vq + v] = val;
            if (val > bm2) { bm2 = val; bi2 = v; }
        }
        bs[tid] = bm2; is_[tid] = bi2;
    }
    __syncthreads();
    for (int st = 128; st > 0; st >>= 1) {
        if (tid < st) {
            float v2 = bs[tid + st]; int i2 = is_[tid + st];
            if (v2 > bs[tid] || (v2 == bs[tid] && i2 < is_[tid])) {
                bs[tid] = v2; is_[tid] = i2;
            }
        }
        __syncthreads();
    }
    float cv1 = bs[0]; int ci1 = Vq + is_[0];
    __syncthreads();

    // --- phase 3: target copy distribution ----------------------------------
    for (int i = tid; i < TDVq; i += 256) accs[i] = 0.f;
    __syncthreads();
    {
        const float* arow = tgt_att + (size_t)row * TDVq;
        const int*   ib   = tidx + b * TDVq;
        for (int s2 = tid; s2 < TDVq; s2 += 256)
            atomicAdd(&accs[ib[s2]], arow[s2]);
    }
    __syncthreads();
    {
        float pc = p[row * 3 + 1];
        float bm2 = -INFINITY; int bi2 = 0;
        for (int v = tid; v < TDVq; v += 256) {
            float val = accs[v] * pc;
            orow[Vq + SDVq + v] = val;
            if (val > bm2) { bm2 = val; bi2 = v; }
        }
        bs[tid] = bm2; is_[tid] = bi2;
    }
    __syncthreads();
    for (int st = 128; st > 0; st >>= 1) {
        if (tid < st) {
            float v2 = bs[tid + st]; int i2 = is_[tid + st];
            if (v2 > bs[tid] || (v2 == bs[tid] && i2 < is_[tid])) {
                bs[tid] = v2; is_[tid] = i2;
            }
        }
        __syncthreads();
    }

    // --- phase 4: combine (first-index-wins on ties via region order) -------
    if (tid == 0) {
        float cv2 = bs[0]; int ci2 = Vq + SDVq + is_[0];
        float v = cv0; int i = ci0;
        if (cv1 > v) { v = cv1; i = ci1; }
        if (cv2 > v) { v = cv2; i = ci2; }
        pred[row] = (float)i;
    }
}

// -------------------------------------------------------------------------
extern "C" void kernel_launch(void* const* d_in, const int* in_sizes, int n_in,
                              void* d_out, int out_size, void* d_ws, size_t ws_size,
                              hipStream_t stream) {
    const float* hiddens = (const float*)d_in[0];
    const float* Wp      = (const float*)d_in[1];
    const float* bp      = (const float*)d_in[2];
    const float* Wv      = (const float*)d_in[3];
    const float* bv      = (const float*)d_in[4];
    const float* src_att = (const float*)d_in[5];
    const float* src_map = (const float*)d_in[6];
    const float* tgt_att = (const float*)d_in[7];
    const float* tgt_map = (const float*)d_in[8];

    float* out  = (float*)d_out;
    float* pred = out + (size_t)ROWS * OUTW;

    // workspace layout (bytes)
    char* ws = (char*)d_ws;
    float* p_ws    = (float*)(ws);                        // 24 KB
    int*   sidx    = (int*)(ws + (24 << 10));             // 8 KB
    int*   tidx    = (int*)(ws + (32 << 10));             // 8 KB
    float* partial = (float*)(ws + (64 << 10));           // 2048*512*4 = 4 MB
    __hip_bfloat16* A_bf = (__hip_bfloat16*)(ws + (8 << 20));    // 2 MB
    __hip_bfloat16* e_bf = (__hip_bfloat16*)(ws + (12 << 20));   // 125 MB
    __hip_bfloat16* Wt   = (__hip_bfloat16*)(ws + (144 << 20));  // 32.75 MB

    // conversions
    convert_a<<<ROWS * Hq / 4 / 256, 256, 0, stream>>>(hiddens, A_bf);
    {
        dim3 tg(Vq / 32, Hq / 32);   // (1000, 16)
        dim3 tb(32, 8);
        transpose_wv<<<tg, tb, 0, stream>>>(Wv, Wt);
    }

    // gate probabilities + one-hot indices
    compute_p<<<ROWS, 64, 0, stream>>>(hiddens, Wp, bp, p_ws);
    extract_idx<<<Bq * Sq, 64, 0, stream>>>(src_map, SDVq, sidx);
    extract_idx<<<Bq * Tq, 64, 0, stream>>>(tgt_map, TDVq, tidx);

    // persistent GEMM with fused exp+bias epilogue; writes bf16 e +
    // per-(nb,wc) row-sum partials (transposed layout, no atomics).
    gemm_persist<<<GBLK, 256, 0, stream>>>(A_bf, Wt, bv, e_bf, partial);

    // fused tail: normalize+write vocab, both scatters, predictions
    finalize<<<ROWS, 256, 0, stream>>>(e_bf, partial, p_ws,
                                       src_att, sidx, tgt_att, tidx, out, pred);
}